// Round 9
// baseline (2817.769 us; speedup 1.0000x reference)
//
#include <hip/hip_runtime.h>
#include <cstdint>

// Problem constants
#define BB 64
#define TT 1024
#define DD 256
#define HH 128
#define G4 512   // 4*H
#define NTAG 3

typedef __attribute__((ext_vector_type(8))) short bf16x8;
typedef __attribute__((ext_vector_type(4))) float f32x4;
typedef __attribute__((ext_vector_type(4))) int i32x4;

__device__ __forceinline__ unsigned short f2bf(float f) {
    uint32_t u = __builtin_bit_cast(uint32_t, f);
    uint32_t r = (u + 0x7FFFu + ((u >> 16) & 1u)) >> 16;
    return (unsigned short)r;
}
__device__ __forceinline__ float bf2f(unsigned short s) {
    uint32_t u = ((uint32_t)s) << 16;
    return __builtin_bit_cast(float, u);
}
// raw HW transcendentals: v_exp_f32 / v_rcp_f32
__device__ __forceinline__ float sigm(float x) {
    return __builtin_amdgcn_rcpf(1.f + __builtin_amdgcn_exp2f(x * -1.44269504f));
}
__device__ __forceinline__ float tanh_f(float x) {
    return 1.f - 2.f * __builtin_amdgcn_rcpf(1.f + __builtin_amdgcn_exp2f(x * 2.88539008f));
}

// LDS-only barrier (no vmem drain) — scan kernel only.
__device__ __forceinline__ void block_sync_lds() {
    __builtin_amdgcn_s_waitcnt(0xC07F);
    __builtin_amdgcn_s_barrier();
}

// async global->LDS, 16B per lane; lds base must be wave-uniform (dest = base + lane*16)
#define ASYNC16(gp, lp) \
    __builtin_amdgcn_global_load_lds((const __attribute__((address_space(1))) unsigned int*)(gp), \
                                     (__attribute__((address_space(3))) unsigned int*)(lp), 16, 0, 0)

// ---------------- fp32 -> bf16 conversion (vectorized x4) ----------------
__global__ void cvt4_kernel(const float* __restrict__ in, unsigned short* __restrict__ out, int n4) {
    int idx = blockIdx.x * blockDim.x + threadIdx.x;
    if (idx < n4) {
        float4 v = ((const float4*)in)[idx];
        ushort4 o;
        o.x = f2bf(v.x); o.y = f2bf(v.y); o.z = f2bf(v.z); o.w = f2bf(v.w);
        ((ushort4*)out)[idx] = o;
    }
}

// ---------------- w_ih convert + row permute: W'[h*4+g][k] = bf16(W[g*128+h][k]) ----------------
// Makes the gemm's N dimension the gate-interleaved n' axis, so the transposed-tile
// epilogue stores directly into gate-interleaved G with contiguous ushort4 writes.
__global__ void cvtperm_kernel(const float* __restrict__ in, unsigned short* __restrict__ out) {
    const int idx = blockIdx.x * 256 + threadIdx.x;  // 512 rows * 64 float4 cols = 32768
    const int np = idx >> 6;
    const int k4 = idx & 63;
    const int g = np & 3, h = np >> 2;
    float4 v = ((const float4*)(in + (size_t)(g * 128 + h) * DD))[k4];
    ushort4 o;
    o.x = f2bf(v.x); o.y = f2bf(v.y); o.z = f2bf(v.z); o.w = f2bf(v.w);
    ((ushort4*)(out + (size_t)np * DD))[k4] = o;
}

// ---------------- input-projection GEMM (LDS-staged, transposed-tile epilogue) ----------------
// G = A @ W'^T + bias.  A: [65536,256] bf16. W': [512,256] bf16 (n' = hcol*4+gate).
// G layout: [row][hcol*4+gate] — the scan reads all 4 gates of one hcol as one 8B load.
// grid (512, 4, 2): x = 128-row M tile, y = 128-col n' strip, z = dir. 4 waves (2x2).
// Epilogue uses operand-swapped MFMA (G^T tile): thread holds 4 consecutive n' cols.
__global__ __launch_bounds__(256) void gemm_ih(
    const unsigned short* __restrict__ A,
    const unsigned short* __restrict__ W0, const unsigned short* __restrict__ W1,
    const float* __restrict__ bih0, const float* __restrict__ bhh0,
    const float* __restrict__ bih1, const float* __restrict__ bhh1,
    unsigned short* __restrict__ G0, unsigned short* __restrict__ G1)
{
    const int dir = blockIdx.z;
    const unsigned short* W = dir ? W1 : W0;
    const float* bih = dir ? bih1 : bih0;
    const float* bhh = dir ? bhh1 : bhh0;
    unsigned short* G = dir ? G1 : G0;

    const int nstrip = blockIdx.y;      // n' in [nstrip*128, nstrip*128+128)
    const int m0 = blockIdx.x * 128;

    const int tid = threadIdx.x;
    const int wv = tid >> 6;
    const int lane = tid & 63;
    const int m16 = lane & 15;
    const int quad = lane >> 4;
    const int wave_m = wv & 1;
    const int wave_n = wv >> 1;

    __shared__ __align__(16) unsigned short As[128 * 64];
    __shared__ __align__(16) unsigned short Bs[128 * 64];

    f32x4 acc[4][4];
#pragma unroll
    for (int i = 0; i < 4; i++)
#pragma unroll
        for (int j = 0; j < 4; j++) acc[i][j] = (f32x4){0.f, 0.f, 0.f, 0.f};

    const int lrow = lane >> 3;          // 0..7: row within 8-row segment
    const int lcol = (lane & 7) * 8;     // k element offset (8 bf16 = 16B)

    for (int kt = 0; kt < 4; kt++) {
#pragma unroll
        for (int it = 0; it < 4; it++) {
            const int seg = wv * 4 + it;
            const int row = seg * 8 + lrow;
            ASYNC16(A + (size_t)(m0 + row) * DD + kt * 64 + lcol, As + seg * 512);
            ASYNC16(W + (size_t)(nstrip * 128 + row) * DD + kt * 64 + lcol, Bs + seg * 512);
        }
        __syncthreads();   // drains vmcnt -> staged data visible

#pragma unroll
        for (int kk = 0; kk < 2; kk++) {
            bf16x8 a[4], b[4];
#pragma unroll
            for (int i = 0; i < 4; i++) {
                const int row = wave_m * 64 + i * 16 + m16;
                a[i] = __builtin_bit_cast(bf16x8, *(const uint4*)&As[row * 64 + kk * 32 + quad * 8]);
            }
#pragma unroll
            for (int j = 0; j < 4; j++) {
                const int row = wave_n * 64 + j * 16 + m16;
                b[j] = __builtin_bit_cast(bf16x8, *(const uint4*)&Bs[row * 64 + kk * 32 + quad * 8]);
            }
            // operand swap: D = W'_tile * A_tile^T = G^T tile
#pragma unroll
            for (int i = 0; i < 4; i++)
#pragma unroll
                for (int j = 0; j < 4; j++)
                    acc[i][j] = __builtin_amdgcn_mfma_f32_16x16x32_bf16(b[j], a[i], acc[i][j], 0, 0, 0);
        }
        __syncthreads();   // tile consumed; safe to restage
    }

    // epilogue: bias (decoded from n') + contiguous ushort4 stores into interleaved G
    float bias[4][4];
#pragma unroll
    for (int j = 0; j < 4; j++)
#pragma unroll
        for (int r = 0; r < 4; r++) {
            const int np = nstrip * 128 + wave_n * 64 + j * 16 + quad * 4 + r;
            const int g = np & 3, h = np >> 2;
            bias[j][r] = bih[g * 128 + h] + bhh[g * 128 + h];
        }
#pragma unroll
    for (int i = 0; i < 4; i++) {
        const int row = m0 + wave_m * 64 + i * 16 + m16;     // G row (from C col)
#pragma unroll
        for (int j = 0; j < 4; j++) {
            const int colbase = nstrip * 128 + wave_n * 64 + j * 16 + quad * 4;
            ushort4 v;
            v.x = f2bf(acc[i][j][0] + bias[j][0]);
            v.y = f2bf(acc[i][j][1] + bias[j][1]);
            v.z = f2bf(acc[i][j][2] + bias[j][2]);
            v.w = f2bf(acc[i][j][3] + bias[j][3]);
            *(ushort4*)(G + (size_t)row * G4 + colbase) = v;
        }
    }
}

// ---------------- MFMA LSTM recurrent scan (i8, 4 waves) ----------------
// grid (64, 2). 256 threads = 4 waves. Wave wv owns hcol groups {2wv, 2wv+1} (32 hcols)
// for ALL 4 gates: 8 N-tiles (g,u), n = g*128 + (2wv+u)*16 + n16; 16 MFMA/wave/step.
// Broadcast-A trick: all A rows = h -> all C rows equal -> every lane holds the gate
// value for its n16 col; dense phase runs in quads 0,1 (q = quad&1 selects hcol group).
// w_hh quantized i8 scale 1024; h i8 scale 127; G (gate-interleaved) prefetched depth 4.
__global__ __launch_bounds__(256) void lstm_scan_mfma(
    const unsigned short* __restrict__ Gf, const unsigned short* __restrict__ Gr,
    const float* __restrict__ whh_f, const float* __restrict__ whh_r,
    unsigned short* __restrict__ out)
{
    const int b = blockIdx.x;
    const int dir = blockIdx.y;
    const unsigned short* G = dir ? Gr : Gf;
    const float* W = dir ? whh_r : whh_f;

    const int tid = threadIdx.x;
    const int wv = tid >> 6;        // 0..3
    const int lane = tid & 63;
    const int n16 = lane & 15;
    const int quad = lane >> 4;
    const int q = quad & 1;         // hcol group within wave (quads 2,3 mirror 0,1)

    __shared__ __align__(16) signed char h8[2][HH];

    // i8 b-fragments: tile (g,u) covers n = g*128 + (2wv+u)*16 + n16; k = kc*64+quad*16+j
    i32x4 bfrag[4][2][2];
#pragma unroll
    for (int g = 0; g < 4; g++)
#pragma unroll
        for (int u = 0; u < 2; u++) {
            const int n = g * 128 + (2 * wv + u) * 16 + n16;
            const float* Wr = W + (size_t)n * HH;
#pragma unroll
            for (int kc = 0; kc < 2; kc++) {
                union { signed char c[16]; i32x4 v; } uu;
#pragma unroll
                for (int j = 0; j < 16; j++) {
                    float w = Wr[kc * 64 + quad * 16 + j] * 1024.f;
                    int qq = (int)rintf(w);
                    qq = qq > 127 ? 127 : (qq < -127 ? -127 : qq);
                    uu.c[j] = (signed char)qq;
                }
                bfrag[g][u][kc] = uu.v;
            }
        }

    if (tid < HH) h8[0][tid] = 0;

    const int hcol = (2 * wv + q) * 16 + n16;
    float c = 0.f;
    const float INV = 1.f / 130048.f;   // 1/(1024*127)

    // per-lane G base: 4 contiguous gate preacts for this hcol (quads 2,3 duplicate 0,1)
    const unsigned short* gb = G + (size_t)b * TT * G4 + hcol * 4;

    ushort4 gq[4];
#pragma unroll
    for (int d = 0; d < 4; d++) {
        const int t = dir ? (TT - 1 - d) : d;
        gq[d] = *(const ushort4*)(gb + (size_t)t * G4);
    }
    block_sync_lds();

    for (int sb = 0; sb < TT; sb += 4) {
#pragma unroll
        for (int d = 0; d < 4; d++) {
            const int s = sb + d;
            const int t = dir ? (TT - 1 - s) : s;
            const int buf = s & 1;

            // A fragments: same-address broadcast read of i8 h (all rows = h)
            i32x4 af[2];
#pragma unroll
            for (int kc = 0; kc < 2; kc++)
                af[kc] = __builtin_bit_cast(i32x4, *(const uint4*)&h8[buf][kc * 64 + quad * 16]);

            i32x4 acc[4][2];
#pragma unroll
            for (int g = 0; g < 4; g++)
#pragma unroll
                for (int u = 0; u < 2; u++) {
                    i32x4 a = {0, 0, 0, 0};
                    a = __builtin_amdgcn_mfma_i32_16x16x64_i8(af[0], bfrag[g][u][0], a, 0, 0, 0);
                    a = __builtin_amdgcn_mfma_i32_16x16x64_i8(af[1], bfrag[g][u][1], a, 0, 0, 0);
                    acc[g][u] = a;
                }

            // dense: all lanes compute (quads 2,3 redundant); only quads 0,1 store
            const float gi = (float)acc[0][q][0] * INV + bf2f(gq[d].x);
            const float gf = (float)acc[1][q][0] * INV + bf2f(gq[d].y);
            const float gg = (float)acc[2][q][0] * INV + bf2f(gq[d].z);
            const float go = (float)acc[3][q][0] * INV + bf2f(gq[d].w);
            const float ig = sigm(gi);
            const float fg = sigm(gf);
            const float gt = tanh_f(gg);
            const float og = sigm(go);
            c = fg * c + ig * gt;
            const float h = og * tanh_f(c);
            if (quad < 2) {
                h8[buf ^ 1][hcol] = (signed char)(int)rintf(h * 127.f);
                out[((size_t)b * TT + t) * (2 * HH) + dir * HH + hcol] = f2bf(h);
            }

            // refill slot d with step s+4's preacts (stays in flight across barriers)
            {
                int sn = s + 4;
                int tn = dir ? (TT - 1 - sn) : sn;
                tn = tn < 0 ? 0 : (tn > TT - 1 ? TT - 1 : tn);
                gq[d] = *(const ushort4*)(gb + (size_t)tn * G4);
            }
            block_sync_lds();
        }
    }
}

// ---------------- emissions: out1 [65536,256] bf16 @ fc_w^T [3,256] + fc_b ----------------
__global__ __launch_bounds__(256) void emis_kernel(
    const unsigned short* __restrict__ out1,
    const float* __restrict__ fcw, const float* __restrict__ fcb,
    float* __restrict__ dout)
{
    if (blockIdx.x == 0 && threadIdx.x == 0) dout[0] = 0.f; // init for CRF atomics

    __shared__ float wsm[NTAG * 256];
    for (int i = threadIdx.x; i < NTAG * 256; i += 256) wsm[i] = fcw[i];
    __syncthreads();

    const int bt = blockIdx.x * 256 + threadIdx.x;
    float a0 = fcb[0], a1 = fcb[1], a2 = fcb[2];
    const uint4* row = (const uint4*)(out1 + (size_t)bt * 256);
#pragma unroll 4
    for (int k8 = 0; k8 < 32; k8++) {
        uint4 u = row[k8];
        const int kb = k8 * 8;
        uint32_t p[4] = {u.x, u.y, u.z, u.w};
#pragma unroll
        for (int e = 0; e < 4; e++) {
            float flo = __builtin_bit_cast(float, p[e] << 16);
            float fhi = __builtin_bit_cast(float, p[e] & 0xFFFF0000u);
            const int k = kb + 2 * e;
            a0 = fmaf(flo, wsm[0 * 256 + k], a0);
            a1 = fmaf(flo, wsm[1 * 256 + k], a1);
            a2 = fmaf(flo, wsm[2 * 256 + k], a2);
            a0 = fmaf(fhi, wsm[0 * 256 + k + 1], a0);
            a1 = fmaf(fhi, wsm[1 * 256 + k + 1], a1);
            a2 = fmaf(fhi, wsm[2 * 256 + k + 1], a2);
        }
    }
    dout[1 + (size_t)bt * 3 + 0] = a0;
    dout[1 + (size_t)bt * 3 + 1] = a1;
    dout[1 + (size_t)bt * 3 + 2] = a2;
}

// ---------------- CRF NLL: log-semiring parallel scan ----------------
__device__ __forceinline__ float sel3(int i, float a, float b, float c) {
    return i == 0 ? a : (i == 1 ? b : c);
}
__device__ __forceinline__ float lse3(float a, float b, float c) {
    float m = fmaxf(a, fmaxf(b, c));
    float s = exp2f((a - m) * 1.44269504f) + exp2f((b - m) * 1.44269504f) + exp2f((c - m) * 1.44269504f);
    return m + log2f(s) * 0.69314718f;
}

__global__ __launch_bounds__(64) void crf_kernel(
    const int* __restrict__ tags,
    const float* __restrict__ start, const float* __restrict__ end,
    const float* __restrict__ trans, float* __restrict__ dout)
{
    const int b = blockIdx.x;
    const int th = threadIdx.x;
    const float* em = dout + 1 + (size_t)b * TT * 3;
    const int* tg = tags + (size_t)b * TT;

    float tr[3][3];
#pragma unroll
    for (int i = 0; i < 3; i++)
#pragma unroll
        for (int j = 0; j < 3; j++) tr[i][j] = trans[i * 3 + j];

    float P[3][3];
#pragma unroll
    for (int i = 0; i < 3; i++)
#pragma unroll
        for (int j = 0; j < 3; j++) P[i][j] = (i == j) ? 0.f : -1e30f;

    const int t0 = 1 + 16 * th;
    float numpart = 0.f;
    int tprev = tg[t0 - 1];

    for (int d = 0; d < 16; d++) {
        const int t = t0 + d;
        if (t < TT) {
            const float e0 = em[3 * t + 0], e1 = em[3 * t + 1], e2 = em[3 * t + 2];
            float N[3][3];
#pragma unroll
            for (int i = 0; i < 3; i++) {
                N[i][0] = lse3(P[i][0] + tr[0][0], P[i][1] + tr[1][0], P[i][2] + tr[2][0]) + e0;
                N[i][1] = lse3(P[i][0] + tr[0][1], P[i][1] + tr[1][1], P[i][2] + tr[2][1]) + e1;
                N[i][2] = lse3(P[i][0] + tr[0][2], P[i][1] + tr[1][2], P[i][2] + tr[2][2]) + e2;
            }
#pragma unroll
            for (int i = 0; i < 3; i++)
#pragma unroll
                for (int j = 0; j < 3; j++) P[i][j] = N[i][j];
            const int tc = tg[t];
            numpart += sel3(tc, e0, e1, e2) + sel3(tprev,
                         sel3(tc, tr[0][0], tr[0][1], tr[0][2]),
                         sel3(tc, tr[1][0], tr[1][1], tr[1][2]),
                         sel3(tc, tr[2][0], tr[2][1], tr[2][2]));
            tprev = tc;
        }
    }

#pragma unroll
    for (int off = 1; off < 64; off <<= 1) {
        float Q[3][3];
#pragma unroll
        for (int i = 0; i < 3; i++)
#pragma unroll
            for (int j = 0; j < 3; j++) Q[i][j] = __shfl_xor(P[i][j], off, 64);
        const bool hi = (th & off) != 0;
        float L[3][3], R[3][3];
#pragma unroll
        for (int i = 0; i < 3; i++)
#pragma unroll
            for (int j = 0; j < 3; j++) {
                L[i][j] = hi ? Q[i][j] : P[i][j];
                R[i][j] = hi ? P[i][j] : Q[i][j];
            }
#pragma unroll
        for (int i = 0; i < 3; i++)
#pragma unroll
            for (int j = 0; j < 3; j++)
                P[i][j] = lse3(L[i][0] + R[0][j], L[i][1] + R[1][j], L[i][2] + R[2][j]);
        numpart += __shfl_xor(numpart, off, 64);
    }

    if (th == 0) {
        const int tg0 = tg[0], tgL = tg[TT - 1];
        const float a0 = start[0] + em[0], a1 = start[1] + em[1], a2 = start[2] + em[2];
        const float f0 = lse3(a0 + P[0][0], a1 + P[1][0], a2 + P[2][0]);
        const float f1 = lse3(a0 + P[0][1], a1 + P[1][1], a2 + P[2][1]);
        const float f2 = lse3(a0 + P[0][2], a1 + P[1][2], a2 + P[2][2]);
        const float logZ = lse3(f0 + end[0], f1 + end[1], f2 + end[2]);
        const float num = sel3(tg0, start[0], start[1], start[2]) +
                          sel3(tg0, em[0], em[1], em[2]) + numpart +
                          sel3(tgL, end[0], end[1], end[2]);
        atomicAdd(&dout[0], (logZ - num) * (1.0f / (float)BB));
    }
}

// ---------------- launch ----------------
extern "C" void kernel_launch(void* const* d_in, const int* in_sizes, int n_in,
                              void* d_out, int out_size, void* d_ws, size_t ws_size,
                              hipStream_t stream) {
    const float* x        = (const float*)d_in[0];
    const int*   tags     = (const int*)d_in[1];
    const float* w_ih_l0  = (const float*)d_in[2];
    const float* w_hh_l0  = (const float*)d_in[3];
    const float* b_ih_l0  = (const float*)d_in[4];
    const float* b_hh_l0  = (const float*)d_in[5];
    const float* w_ih_l0r = (const float*)d_in[6];
    const float* w_hh_l0r = (const float*)d_in[7];
    const float* b_ih_l0r = (const float*)d_in[8];
    const float* b_hh_l0r = (const float*)d_in[9];
    const float* w_ih_l1  = (const float*)d_in[10];
    const float* w_hh_l1  = (const float*)d_in[11];
    const float* b_ih_l1  = (const float*)d_in[12];
    const float* b_hh_l1  = (const float*)d_in[13];
    const float* w_ih_l1r = (const float*)d_in[14];
    const float* w_hh_l1r = (const float*)d_in[15];
    const float* b_ih_l1r = (const float*)d_in[16];
    const float* b_hh_l1r = (const float*)d_in[17];
    const float* fc_w     = (const float*)d_in[18];
    const float* fc_b     = (const float*)d_in[19];
    const float* crf_start= (const float*)d_in[20];
    const float* crf_end  = (const float*)d_in[21];
    const float* crf_trans= (const float*)d_in[22];
    float* dout = (float*)d_out;

    uint8_t* ws = (uint8_t*)d_ws;
    unsigned short* xb   = (unsigned short*)(ws + 0);          // 33.5 MB, reused as out1 later
    unsigned short* out1 = xb;
    unsigned short* out0 = (unsigned short*)(ws + 33554432);   // 33.5 MB
    unsigned short* Gf   = (unsigned short*)(ws + 67108864);   // 67 MB, gate-interleaved
    unsigned short* Gr   = (unsigned short*)(ws + 134217728);  // 67 MB
    unsigned short* wb0  = (unsigned short*)(ws + 201326592);  // 4 x 256 KB (permuted W')
    unsigned short* wb0r = wb0 + 131072;
    unsigned short* wb1  = wb0 + 262144;
    unsigned short* wb1r = wb0 + 393216;

    // 1. convert x (plain) and the 4 w_ih matrices (with gate-interleave row permute)
    cvt4_kernel<<<dim3((16777216 / 4 + 255) / 256), dim3(256), 0, stream>>>(x, xb, 16777216 / 4);
    cvtperm_kernel<<<dim3(128), dim3(256), 0, stream>>>(w_ih_l0,  wb0);
    cvtperm_kernel<<<dim3(128), dim3(256), 0, stream>>>(w_ih_l0r, wb0r);
    cvtperm_kernel<<<dim3(128), dim3(256), 0, stream>>>(w_ih_l1,  wb1);
    cvtperm_kernel<<<dim3(128), dim3(256), 0, stream>>>(w_ih_l1r, wb1r);

    // 2. layer 0: input projection + MFMA scan
    gemm_ih<<<dim3(512, 4, 2), dim3(256), 0, stream>>>(
        xb, wb0, wb0r, b_ih_l0, b_hh_l0, b_ih_l0r, b_hh_l0r, Gf, Gr);
    lstm_scan_mfma<<<dim3(64, 2), dim3(256), 0, stream>>>(Gf, Gr, w_hh_l0, w_hh_l0r, out0);

    // 3. layer 1: input projection (reusing G buffers) + MFMA scan
    gemm_ih<<<dim3(512, 4, 2), dim3(256), 0, stream>>>(
        out0, wb1, wb1r, b_ih_l1, b_hh_l1, b_ih_l1r, b_hh_l1r, Gf, Gr);
    lstm_scan_mfma<<<dim3(64, 2), dim3(256), 0, stream>>>(Gf, Gr, w_hh_l1, w_hh_l1r, out1);

    // 4. emissions (also zeroes dout[0] for the CRF atomics)
    emis_kernel<<<dim3(256), dim3(256), 0, stream>>>(out1, fc_w, fc_b, dout);

    // 5. CRF NLL -> dout[0] (parallel scan, one block per batch)
    crf_kernel<<<dim3(64), dim3(64), 0, stream>>>(tags, crf_start, crf_end, crf_trans, dout);
}

// Round 10
// 1025.995 us; speedup vs baseline: 2.7464x; 2.7464x over previous
//
#include <hip/hip_runtime.h>
#include <cstdint>

// Problem constants
#define BB 64
#define TT 1024
#define DD 256
#define HH 128
#define G4 512   // 4*H
#define NTAG 3

typedef __attribute__((ext_vector_type(8))) short bf16x8;
typedef __attribute__((ext_vector_type(4))) float f32x4;
typedef __attribute__((ext_vector_type(4))) int i32x4;

__device__ __forceinline__ unsigned short f2bf(float f) {
    uint32_t u = __builtin_bit_cast(uint32_t, f);
    uint32_t r = (u + 0x7FFFu + ((u >> 16) & 1u)) >> 16;
    return (unsigned short)r;
}
__device__ __forceinline__ float bf2f(unsigned short s) {
    uint32_t u = ((uint32_t)s) << 16;
    return __builtin_bit_cast(float, u);
}
// raw HW transcendentals: v_exp_f32 / v_rcp_f32
__device__ __forceinline__ float sigm(float x) {
    return __builtin_amdgcn_rcpf(1.f + __builtin_amdgcn_exp2f(x * -1.44269504f));
}
__device__ __forceinline__ float tanh_f(float x) {
    return 1.f - 2.f * __builtin_amdgcn_rcpf(1.f + __builtin_amdgcn_exp2f(x * 2.88539008f));
}

// LDS-only barrier (no vmem drain) — scan kernel only.
__device__ __forceinline__ void block_sync_lds() {
    __builtin_amdgcn_s_waitcnt(0xC07F);
    __builtin_amdgcn_s_barrier();
}

// async global->LDS, 16B per lane; lds base must be wave-uniform (dest = base + lane*16)
#define ASYNC16(gp, lp) \
    __builtin_amdgcn_global_load_lds((const __attribute__((address_space(1))) unsigned int*)(gp), \
                                     (__attribute__((address_space(3))) unsigned int*)(lp), 16, 0, 0)

// ---------------- fp32 -> bf16 conversion (vectorized x4) ----------------
__global__ void cvt4_kernel(const float* __restrict__ in, unsigned short* __restrict__ out, int n4) {
    int idx = blockIdx.x * blockDim.x + threadIdx.x;
    if (idx < n4) {
        float4 v = ((const float4*)in)[idx];
        ushort4 o;
        o.x = f2bf(v.x); o.y = f2bf(v.y); o.z = f2bf(v.z); o.w = f2bf(v.w);
        ((ushort4*)out)[idx] = o;
    }
}

// ---------------- w_ih convert + row permute: W'[h*4+g][k] = bf16(W[g*128+h][k]) ----------------
__global__ void cvtperm_kernel(const float* __restrict__ in, unsigned short* __restrict__ out) {
    const int idx = blockIdx.x * 256 + threadIdx.x;  // 512 rows * 64 float4 cols = 32768
    const int np = idx >> 6;
    const int k4 = idx & 63;
    const int g = np & 3, h = np >> 2;
    float4 v = ((const float4*)(in + (size_t)(g * 128 + h) * DD))[k4];
    ushort4 o;
    o.x = f2bf(v.x); o.y = f2bf(v.y); o.z = f2bf(v.z); o.w = f2bf(v.w);
    ((ushort4*)(out + (size_t)np * DD))[k4] = o;
}

// ---------------- input-projection GEMM (LDS-staged, transposed-tile epilogue) ----------------
// G = A @ W'^T + bias.  A: [65536,256] bf16. W': [512,256] bf16 (n' = hcol*4+gate).
// G layout: [row][hcol*4+gate] — the scan reads all 4 gates of one hcol as one 8B load.
// grid (512, 4, 2): x = 128-row M tile, y = 128-col n' strip, z = dir. 4 waves (2x2).
// Epilogue uses operand-swapped MFMA (G^T tile): thread holds 4 consecutive n' cols.
__global__ __launch_bounds__(256) void gemm_ih(
    const unsigned short* __restrict__ A,
    const unsigned short* __restrict__ W0, const unsigned short* __restrict__ W1,
    const float* __restrict__ bih0, const float* __restrict__ bhh0,
    const float* __restrict__ bih1, const float* __restrict__ bhh1,
    unsigned short* __restrict__ G0, unsigned short* __restrict__ G1)
{
    const int dir = blockIdx.z;
    const unsigned short* W = dir ? W1 : W0;
    const float* bih = dir ? bih1 : bih0;
    const float* bhh = dir ? bhh1 : bhh0;
    unsigned short* G = dir ? G1 : G0;

    const int nstrip = blockIdx.y;      // n' in [nstrip*128, nstrip*128+128)
    const int m0 = blockIdx.x * 128;

    const int tid = threadIdx.x;
    const int wv = tid >> 6;
    const int lane = tid & 63;
    const int m16 = lane & 15;
    const int quad = lane >> 4;
    const int wave_m = wv & 1;
    const int wave_n = wv >> 1;

    __shared__ __align__(16) unsigned short As[128 * 64];
    __shared__ __align__(16) unsigned short Bs[128 * 64];

    f32x4 acc[4][4];
#pragma unroll
    for (int i = 0; i < 4; i++)
#pragma unroll
        for (int j = 0; j < 4; j++) acc[i][j] = (f32x4){0.f, 0.f, 0.f, 0.f};

    const int lrow = lane >> 3;          // 0..7: row within 8-row segment
    const int lcol = (lane & 7) * 8;     // k element offset (8 bf16 = 16B)

    for (int kt = 0; kt < 4; kt++) {
#pragma unroll
        for (int it = 0; it < 4; it++) {
            const int seg = wv * 4 + it;
            const int row = seg * 8 + lrow;
            ASYNC16(A + (size_t)(m0 + row) * DD + kt * 64 + lcol, As + seg * 512);
            ASYNC16(W + (size_t)(nstrip * 128 + row) * DD + kt * 64 + lcol, Bs + seg * 512);
        }
        __syncthreads();   // drains vmcnt -> staged data visible

#pragma unroll
        for (int kk = 0; kk < 2; kk++) {
            bf16x8 a[4], b[4];
#pragma unroll
            for (int i = 0; i < 4; i++) {
                const int row = wave_m * 64 + i * 16 + m16;
                a[i] = __builtin_bit_cast(bf16x8, *(const uint4*)&As[row * 64 + kk * 32 + quad * 8]);
            }
#pragma unroll
            for (int j = 0; j < 4; j++) {
                const int row = wave_n * 64 + j * 16 + m16;
                b[j] = __builtin_bit_cast(bf16x8, *(const uint4*)&Bs[row * 64 + kk * 32 + quad * 8]);
            }
            // operand swap: D = W'_tile * A_tile^T = G^T tile
#pragma unroll
            for (int i = 0; i < 4; i++)
#pragma unroll
                for (int j = 0; j < 4; j++)
                    acc[i][j] = __builtin_amdgcn_mfma_f32_16x16x32_bf16(b[j], a[i], acc[i][j], 0, 0, 0);
        }
        __syncthreads();   // tile consumed; safe to restage
    }

    // epilogue: bias (decoded from n') + contiguous ushort4 stores into interleaved G
    float bias[4][4];
#pragma unroll
    for (int j = 0; j < 4; j++)
#pragma unroll
        for (int r = 0; r < 4; r++) {
            const int np = nstrip * 128 + wave_n * 64 + j * 16 + quad * 4 + r;
            const int g = np & 3, h = np >> 2;
            bias[j][r] = bih[g * 128 + h] + bhh[g * 128 + h];
        }
#pragma unroll
    for (int i = 0; i < 4; i++) {
        const int row = m0 + wave_m * 64 + i * 16 + m16;     // G row (from C col)
#pragma unroll
        for (int j = 0; j < 4; j++) {
            const int colbase = nstrip * 128 + wave_n * 64 + j * 16 + quad * 4;
            ushort4 v;
            v.x = f2bf(acc[i][j][0] + bias[j][0]);
            v.y = f2bf(acc[i][j][1] + bias[j][1]);
            v.z = f2bf(acc[i][j][2] + bias[j][2]);
            v.w = f2bf(acc[i][j][3] + bias[j][3]);
            *(ushort4*)(G + (size_t)row * G4 + colbase) = v;
        }
    }
}

// ---------------- MFMA LSTM recurrent scan (i8, 8 waves — R7-proven structure) ----------------
// grid (64, 2). 512 threads = 8 waves; wave wv owns hcols [16wv,16wv+16) for all 4 gates.
// w_hh quantized i8 scale 1024; h i8 scale 127; v_mfma_i32_16x16x64_i8, K=128 in 2 inst.
// Gates in acc regs; h (i8) double-buffered in LDS (broadcast reads); G (gate-interleaved)
// prefetched depth 4 as one 8B load/lane/step; LDS-only barrier keeps vmem in flight.
// NOTE (R9 lesson): 8 waves = 2/SIMD is required — at 1 wave/SIMD all dep-chain stalls
// (ds_read latency, MFMA->VALU, transcendental chain) are exposed and the step tripled.
__global__ __launch_bounds__(512, 2) void lstm_scan_mfma(
    const unsigned short* __restrict__ Gf, const unsigned short* __restrict__ Gr,
    const float* __restrict__ whh_f, const float* __restrict__ whh_r,
    unsigned short* __restrict__ out)
{
    const int b = blockIdx.x;
    const int dir = blockIdx.y;
    const unsigned short* G = dir ? Gr : Gf;
    const float* W = dir ? whh_r : whh_f;

    const int tid = threadIdx.x;
    const int wv = tid >> 6;
    const int lane = tid & 63;
    const int n16 = lane & 15;
    const int quad = lane >> 4;

    __shared__ __align__(16) signed char h8[2][HH];

    i32x4 bfrag[4][2];
#pragma unroll
    for (int p = 0; p < 4; p++) {
        const int n = 128 * p + wv * 16 + n16;
        const float* Wr = W + (size_t)n * HH;
#pragma unroll
        for (int kc = 0; kc < 2; kc++) {
            union { signed char c[16]; i32x4 v; } u;
#pragma unroll
            for (int j = 0; j < 16; j++) {
                float w = Wr[kc * 64 + quad * 16 + j] * 1024.f;
                int q = (int)rintf(w);
                q = q > 127 ? 127 : (q < -127 ? -127 : q);
                u.c[j] = (signed char)q;
            }
            bfrag[p][kc] = u.v;
        }
    }

    if (tid < HH) h8[0][tid] = 0;

    const bool dense = (quad == 0);
    const int hcol = wv * 16 + n16;
    float c = 0.f;
    const float INV = 1.f / 130048.f;   // 1/(1024*127)

    // per-lane G base: 4 contiguous gate preacts for this hcol (quads duplicate -> same lines)
    const unsigned short* gb = G + (size_t)b * TT * G4 + hcol * 4;

    ushort4 gq[4];
#pragma unroll
    for (int d = 0; d < 4; d++) {
        const int t = dir ? (TT - 1 - d) : d;
        gq[d] = *(const ushort4*)(gb + (size_t)t * G4);
    }
    block_sync_lds();

    for (int sb = 0; sb < TT; sb += 4) {
#pragma unroll
        for (int d = 0; d < 4; d++) {
            const int s = sb + d;
            const int t = dir ? (TT - 1 - s) : s;
            const int buf = s & 1;

            i32x4 af[2];
#pragma unroll
            for (int kc = 0; kc < 2; kc++)
                af[kc] = __builtin_bit_cast(i32x4, *(const uint4*)&h8[buf][kc * 64 + quad * 16]);

            i32x4 acc[4];
#pragma unroll
            for (int p = 0; p < 4; p++) {
                i32x4 a = {0, 0, 0, 0};
                a = __builtin_amdgcn_mfma_i32_16x16x64_i8(af[0], bfrag[p][0], a, 0, 0, 0);
                a = __builtin_amdgcn_mfma_i32_16x16x64_i8(af[1], bfrag[p][1], a, 0, 0, 0);
                acc[p] = a;
            }

            if (dense) {
                const float gi = (float)acc[0][0] * INV + bf2f(gq[d].x);
                const float gf = (float)acc[1][0] * INV + bf2f(gq[d].y);
                const float gg = (float)acc[2][0] * INV + bf2f(gq[d].z);
                const float go = (float)acc[3][0] * INV + bf2f(gq[d].w);
                const float ig = sigm(gi);
                const float fg = sigm(gf);
                const float gt = tanh_f(gg);
                const float og = sigm(go);
                c = fg * c + ig * gt;
                const float h = og * tanh_f(c);
                h8[buf ^ 1][hcol] = (signed char)(int)rintf(h * 127.f);
                out[((size_t)b * TT + t) * (2 * HH) + dir * HH + hcol] = f2bf(h);
            }

            {
                int sn = s + 4;
                int tn = dir ? (TT - 1 - sn) : sn;
                tn = tn < 0 ? 0 : (tn > TT - 1 ? TT - 1 : tn);
                gq[d] = *(const ushort4*)(gb + (size_t)tn * G4);
            }
            block_sync_lds();
        }
    }
}

// ---------------- emissions: out1 [65536,256] bf16 @ fc_w^T [3,256] + fc_b ----------------
__global__ __launch_bounds__(256) void emis_kernel(
    const unsigned short* __restrict__ out1,
    const float* __restrict__ fcw, const float* __restrict__ fcb,
    float* __restrict__ dout)
{
    if (blockIdx.x == 0 && threadIdx.x == 0) dout[0] = 0.f; // init for CRF atomics

    __shared__ float wsm[NTAG * 256];
    for (int i = threadIdx.x; i < NTAG * 256; i += 256) wsm[i] = fcw[i];
    __syncthreads();

    const int bt = blockIdx.x * 256 + threadIdx.x;
    float a0 = fcb[0], a1 = fcb[1], a2 = fcb[2];
    const uint4* row = (const uint4*)(out1 + (size_t)bt * 256);
#pragma unroll 4
    for (int k8 = 0; k8 < 32; k8++) {
        uint4 u = row[k8];
        const int kb = k8 * 8;
        uint32_t p[4] = {u.x, u.y, u.z, u.w};
#pragma unroll
        for (int e = 0; e < 4; e++) {
            float flo = __builtin_bit_cast(float, p[e] << 16);
            float fhi = __builtin_bit_cast(float, p[e] & 0xFFFF0000u);
            const int k = kb + 2 * e;
            a0 = fmaf(flo, wsm[0 * 256 + k], a0);
            a1 = fmaf(flo, wsm[1 * 256 + k], a1);
            a2 = fmaf(flo, wsm[2 * 256 + k], a2);
            a0 = fmaf(fhi, wsm[0 * 256 + k + 1], a0);
            a1 = fmaf(fhi, wsm[1 * 256 + k + 1], a1);
            a2 = fmaf(fhi, wsm[2 * 256 + k + 1], a2);
        }
    }
    dout[1 + (size_t)bt * 3 + 0] = a0;
    dout[1 + (size_t)bt * 3 + 1] = a1;
    dout[1 + (size_t)bt * 3 + 2] = a2;
}

// ---------------- CRF NLL: log-semiring parallel scan ----------------
__device__ __forceinline__ float sel3(int i, float a, float b, float c) {
    return i == 0 ? a : (i == 1 ? b : c);
}
__device__ __forceinline__ float lse3(float a, float b, float c) {
    float m = fmaxf(a, fmaxf(b, c));
    float s = exp2f((a - m) * 1.44269504f) + exp2f((b - m) * 1.44269504f) + exp2f((c - m) * 1.44269504f);
    return m + log2f(s) * 0.69314718f;
}

__global__ __launch_bounds__(64) void crf_kernel(
    const int* __restrict__ tags,
    const float* __restrict__ start, const float* __restrict__ end,
    const float* __restrict__ trans, float* __restrict__ dout)
{
    const int b = blockIdx.x;
    const int th = threadIdx.x;
    const float* em = dout + 1 + (size_t)b * TT * 3;
    const int* tg = tags + (size_t)b * TT;

    float tr[3][3];
#pragma unroll
    for (int i = 0; i < 3; i++)
#pragma unroll
        for (int j = 0; j < 3; j++) tr[i][j] = trans[i * 3 + j];

    float P[3][3];
#pragma unroll
    for (int i = 0; i < 3; i++)
#pragma unroll
        for (int j = 0; j < 3; j++) P[i][j] = (i == j) ? 0.f : -1e30f;

    const int t0 = 1 + 16 * th;
    float numpart = 0.f;
    int tprev = tg[t0 - 1];

    for (int d = 0; d < 16; d++) {
        const int t = t0 + d;
        if (t < TT) {
            const float e0 = em[3 * t + 0], e1 = em[3 * t + 1], e2 = em[3 * t + 2];
            float N[3][3];
#pragma unroll
            for (int i = 0; i < 3; i++) {
                N[i][0] = lse3(P[i][0] + tr[0][0], P[i][1] + tr[1][0], P[i][2] + tr[2][0]) + e0;
                N[i][1] = lse3(P[i][0] + tr[0][1], P[i][1] + tr[1][1], P[i][2] + tr[2][1]) + e1;
                N[i][2] = lse3(P[i][0] + tr[0][2], P[i][1] + tr[1][2], P[i][2] + tr[2][2]) + e2;
            }
#pragma unroll
            for (int i = 0; i < 3; i++)
#pragma unroll
                for (int j = 0; j < 3; j++) P[i][j] = N[i][j];
            const int tc = tg[t];
            numpart += sel3(tc, e0, e1, e2) + sel3(tprev,
                         sel3(tc, tr[0][0], tr[0][1], tr[0][2]),
                         sel3(tc, tr[1][0], tr[1][1], tr[1][2]),
                         sel3(tc, tr[2][0], tr[2][1], tr[2][2]));
            tprev = tc;
        }
    }

#pragma unroll
    for (int off = 1; off < 64; off <<= 1) {
        float Q[3][3];
#pragma unroll
        for (int i = 0; i < 3; i++)
#pragma unroll
            for (int j = 0; j < 3; j++) Q[i][j] = __shfl_xor(P[i][j], off, 64);
        const bool hi = (th & off) != 0;
        float L[3][3], R[3][3];
#pragma unroll
        for (int i = 0; i < 3; i++)
#pragma unroll
            for (int j = 0; j < 3; j++) {
                L[i][j] = hi ? Q[i][j] : P[i][j];
                R[i][j] = hi ? P[i][j] : Q[i][j];
            }
#pragma unroll
        for (int i = 0; i < 3; i++)
#pragma unroll
            for (int j = 0; j < 3; j++)
                P[i][j] = lse3(L[i][0] + R[0][j], L[i][1] + R[1][j], L[i][2] + R[2][j]);
        numpart += __shfl_xor(numpart, off, 64);
    }

    if (th == 0) {
        const int tg0 = tg[0], tgL = tg[TT - 1];
        const float a0 = start[0] + em[0], a1 = start[1] + em[1], a2 = start[2] + em[2];
        const float f0 = lse3(a0 + P[0][0], a1 + P[1][0], a2 + P[2][0]);
        const float f1 = lse3(a0 + P[0][1], a1 + P[1][1], a2 + P[2][1]);
        const float f2 = lse3(a0 + P[0][2], a1 + P[1][2], a2 + P[2][2]);
        const float logZ = lse3(f0 + end[0], f1 + end[1], f2 + end[2]);
        const float num = sel3(tg0, start[0], start[1], start[2]) +
                          sel3(tg0, em[0], em[1], em[2]) + numpart +
                          sel3(tgL, end[0], end[1], end[2]);
        atomicAdd(&dout[0], (logZ - num) * (1.0f / (float)BB));
    }
}

// ---------------- launch ----------------
extern "C" void kernel_launch(void* const* d_in, const int* in_sizes, int n_in,
                              void* d_out, int out_size, void* d_ws, size_t ws_size,
                              hipStream_t stream) {
    const float* x        = (const float*)d_in[0];
    const int*   tags     = (const int*)d_in[1];
    const float* w_ih_l0  = (const float*)d_in[2];
    const float* w_hh_l0  = (const float*)d_in[3];
    const float* b_ih_l0  = (const float*)d_in[4];
    const float* b_hh_l0  = (const float*)d_in[5];
    const float* w_ih_l0r = (const float*)d_in[6];
    const float* w_hh_l0r = (const float*)d_in[7];
    const float* b_ih_l0r = (const float*)d_in[8];
    const float* b_hh_l0r = (const float*)d_in[9];
    const float* w_ih_l1  = (const float*)d_in[10];
    const float* w_hh_l1  = (const float*)d_in[11];
    const float* b_ih_l1  = (const float*)d_in[12];
    const float* b_hh_l1  = (const float*)d_in[13];
    const float* w_ih_l1r = (const float*)d_in[14];
    const float* w_hh_l1r = (const float*)d_in[15];
    const float* b_ih_l1r = (const float*)d_in[16];
    const float* b_hh_l1r = (const float*)d_in[17];
    const float* fc_w     = (const float*)d_in[18];
    const float* fc_b     = (const float*)d_in[19];
    const float* crf_start= (const float*)d_in[20];
    const float* crf_end  = (const float*)d_in[21];
    const float* crf_trans= (const float*)d_in[22];
    float* dout = (float*)d_out;

    uint8_t* ws = (uint8_t*)d_ws;
    unsigned short* xb   = (unsigned short*)(ws + 0);          // 33.5 MB, reused as out1 later
    unsigned short* out1 = xb;
    unsigned short* out0 = (unsigned short*)(ws + 33554432);   // 33.5 MB
    unsigned short* Gf   = (unsigned short*)(ws + 67108864);   // 67 MB, gate-interleaved
    unsigned short* Gr   = (unsigned short*)(ws + 134217728);  // 67 MB
    unsigned short* wb0  = (unsigned short*)(ws + 201326592);  // 4 x 256 KB (permuted W')
    unsigned short* wb0r = wb0 + 131072;
    unsigned short* wb1  = wb0 + 262144;
    unsigned short* wb1r = wb0 + 393216;

    // 1. convert x (plain) and the 4 w_ih matrices (with gate-interleave row permute)
    cvt4_kernel<<<dim3((16777216 / 4 + 255) / 256), dim3(256), 0, stream>>>(x, xb, 16777216 / 4);
    cvtperm_kernel<<<dim3(128), dim3(256), 0, stream>>>(w_ih_l0,  wb0);
    cvtperm_kernel<<<dim3(128), dim3(256), 0, stream>>>(w_ih_l0r, wb0r);
    cvtperm_kernel<<<dim3(128), dim3(256), 0, stream>>>(w_ih_l1,  wb1);
    cvtperm_kernel<<<dim3(128), dim3(256), 0, stream>>>(w_ih_l1r, wb1r);

    // 2. layer 0: input projection + MFMA scan
    gemm_ih<<<dim3(512, 4, 2), dim3(256), 0, stream>>>(
        xb, wb0, wb0r, b_ih_l0, b_hh_l0, b_ih_l0r, b_hh_l0r, Gf, Gr);
    lstm_scan_mfma<<<dim3(64, 2), dim3(512), 0, stream>>>(Gf, Gr, w_hh_l0, w_hh_l0r, out0);

    // 3. layer 1: input projection (reusing G buffers) + MFMA scan
    gemm_ih<<<dim3(512, 4, 2), dim3(256), 0, stream>>>(
        out0, wb1, wb1r, b_ih_l1, b_hh_l1, b_ih_l1r, b_hh_l1r, Gf, Gr);
    lstm_scan_mfma<<<dim3(64, 2), dim3(512), 0, stream>>>(Gf, Gr, w_hh_l1, w_hh_l1r, out1);

    // 4. emissions (also zeroes dout[0] for the CRF atomics)
    emis_kernel<<<dim3(256), dim3(256), 0, stream>>>(out1, fc_w, fc_b, dout);

    // 5. CRF NLL -> dout[0] (parallel scan, one block per batch)
    crf_kernel<<<dim3(64), dim3(64), 0, stream>>>(tags, crf_start, crf_end, crf_trans, dout);
}